// Round 3
// 122.880 us; speedup vs baseline: 1.0162x; 1.0162x over previous
//
#include <hip/hip_runtime.h>
#include <math.h>

#define N_NODES 100000
#define N_EDGES 1250000
#define IN_DIM 6
#define HID 64

#define BIN_SHIFT 8
#define BIN_NODES 256
#define NBIN 391                     // ceil(100000/256)
#define A_BLOCKS 250
#define EPB (N_EDGES / A_BLOCKS)     // 5000 exactly
#define CAP 4096                     // per-bin region capacity (max count ~3460)
#define SOFF (NBIN * CAP)            // src-chain region offset in rec

// bf16 <-> f32 helpers
__device__ inline float lo16(unsigned u) { return __uint_as_float(u << 16); }
__device__ inline float hi16(unsigned u) { return __uint_as_float(u & 0xffff0000u); }
__device__ inline unsigned short f2bf(float f) {
    unsigned u = __float_as_uint(f);
    u += 0x7FFFu + ((u >> 16) & 1u);
    return (unsigned short)(u >> 16);
}
__device__ inline unsigned pack2(float a, float b) {
    return (unsigned)f2bf(a) | ((unsigned)f2bf(b) << 16);
}

// --- binFill: register-held edges + block-local counting sort in LDS -------
// Two rounds (dst-chain then src-chain). Per round:
//   hist -> wave0 shuffle-scan of 391 bin counts -> LDS bucket-grouped
//   scatter (with precomputed global positions) -> coalesced write-out.
// Hardened: scatter index clamped to [0,EPB); global write bound-checked,
// so any logic bug shows as a wrong answer, never a memory fault.
// recD (bin b at [b*CAP, b*CAP+cntD)) = (dstLow<<17)|src
// recS (bin b at [SOFF+b*CAP, ...))   = (srcLow<<17)|dst
__global__ __launch_bounds__(1024) void binFill(const int* __restrict__ src,
                                                const int* __restrict__ dst,
                                                int* __restrict__ cnt,
                                                unsigned* __restrict__ rec) {
    __shared__ int lc[NBIN];          // counts, then local cursors
    __shared__ int scv[NBIN];         // count snapshot for scan
    __shared__ int lb[NBIN];          // global base per bin (this block's segment)
    __shared__ int lbase[NBIN];       // local (LDS) exclusive base per bin
    __shared__ unsigned ldsRec[EPB];  // 20 KB bucket-grouped records
    __shared__ int ldsPos[EPB];       // 20 KB global positions

    int t = threadIdx.x;
    int base = blockIdx.x * EPB;

    // single global read: hold this thread's edges in registers
    int4 dA = *(const int4*)&dst[base + t * 4];
    int4 sA = *(const int4*)&src[base + t * 4];
    const int TB = (EPB - 4096) / 4;  // 226 threads own a second quad
    bool hasB = (t < TB);
    int4 dB = make_int4(0, 0, 0, 0), sB = make_int4(0, 0, 0, 0);
    if (hasB) {
        dB = *(const int4*)&dst[base + 4096 + t * 4];
        sB = *(const int4*)&src[base + 4096 + t * 4];
    }

#define HIST4(v4) do {                                  \
        atomicAdd(&lc[(v4).x >> BIN_SHIFT], 1);         \
        atomicAdd(&lc[(v4).y >> BIN_SHIFT], 1);         \
        atomicAdd(&lc[(v4).z >> BIN_SHIFT], 1);         \
        atomicAdd(&lc[(v4).w >> BIN_SHIFT], 1);         \
    } while (0)

#define SCAT1(key, val) do {                                                  \
        int b_ = (key) >> BIN_SHIFT;                                          \
        int loc_ = lbase[b_] + atomicAdd(&lc[b_], 1);                         \
        loc_ = min(loc_, EPB - 1);                                            \
        ldsRec[loc_] = ((unsigned)((key) & (BIN_NODES - 1)) << 17)            \
                     | (unsigned)(val);                                       \
        ldsPos[loc_] = lb[b_] + (loc_ - lbase[b_]);                           \
    } while (0)

#define SCAT4(k4, v4) do {                  \
        SCAT1((k4).x, (v4).x);              \
        SCAT1((k4).y, (v4).y);              \
        SCAT1((k4).z, (v4).z);              \
        SCAT1((k4).w, (v4).w);              \
    } while (0)

#define WRITEOUT() do {                                                       \
        for (int i = t; i < EPB; i += 1024) {                                 \
            unsigned p_ = (unsigned)ldsPos[i];                                \
            if (p_ < (unsigned)(2 * SOFF)) rec[p_] = ldsRec[i];               \
        }                                                                     \
    } while (0)

    // ======================= round A: dst-chain ========================
    if (t < NBIN) lc[t] = 0;
    __syncthreads();
    HIST4(dA);
    if (hasB) HIST4(dB);
    __syncthreads();
    if (t < NBIN) {
        int c = lc[t];
        scv[t] = c;
        lc[t] = 0;                                    // becomes cursor
        int off = (c > 0) ? atomicAdd(&cnt[t], c) : 0;
        lb[t] = t * CAP + off;
    }
    __syncthreads();
    if (t < 64) {                                     // wave0 exclusive scan
        int carry = 0;
#pragma unroll
        for (int cb = 0; cb < NBIN; cb += 64) {
            int idx = cb + t;
            int c = (idx < NBIN) ? scv[idx] : 0;
            int v = c;
#pragma unroll
            for (int off = 1; off < 64; off <<= 1) {
                int u = __shfl_up(v, off, 64);
                if (t >= off) v += u;
            }
            if (idx < NBIN) lbase[idx] = carry + v - c;
            carry += __shfl(v, 63, 64);
        }
    }
    __syncthreads();
    SCAT4(dA, sA);
    if (hasB) SCAT4(dB, sB);
    __syncthreads();
    WRITEOUT();
    __syncthreads();

    // ======================= round B: src-chain ========================
    if (t < NBIN) lc[t] = 0;
    __syncthreads();
    HIST4(sA);
    if (hasB) HIST4(sB);
    __syncthreads();
    if (t < NBIN) {
        int c = lc[t];
        scv[t] = c;
        lc[t] = 0;
        int off = (c > 0) ? atomicAdd(&cnt[NBIN + t], c) : 0;
        lb[t] = SOFF + t * CAP + off;
    }
    __syncthreads();
    if (t < 64) {
        int carry = 0;
#pragma unroll
        for (int cb = 0; cb < NBIN; cb += 64) {
            int idx = cb + t;
            int c = (idx < NBIN) ? scv[idx] : 0;
            int v = c;
#pragma unroll
            for (int off = 1; off < 64; off <<= 1) {
                int u = __shfl_up(v, off, 64);
                if (t >= off) v += u;
            }
            if (idx < NBIN) lbase[idx] = carry + v - c;
            carry += __shfl(v, 63, 64);
        }
    }
    __syncthreads();
    SCAT4(sA, dA);
    if (hasB) SCAT4(sB, dB);
    __syncthreads();
    WRITEOUT();

#undef HIST4
#undef SCAT1
#undef SCAT4
#undef WRITEOUT
}

// --- disXH: per dst-bin 4-way hist -> deg, dis, xpad -----------------------
__global__ __launch_bounds__(1024) void disXH(const unsigned* __restrict__ rec,
                                              const int* __restrict__ cnt,
                                              const float* __restrict__ x,
                                              int* __restrict__ deg,
                                              float* __restrict__ dis,
                                              uint4* __restrict__ xpad) {
    __shared__ int histS[4][BIN_NODES];
    int t = threadIdx.x, g = t >> 8;
    if (t < 4 * BIN_NODES) ((int*)histS)[t] = 0;
    __syncthreads();
    int bin = blockIdx.x;
    int beg = bin * CAP, end = beg + cnt[bin];
    for (int j = beg + t; j < end; j += 1024) atomicAdd(&histS[g][rec[j] >> 17], 1);
    __syncthreads();
    if (t < BIN_NODES) {
        int n = (bin << BIN_SHIFT) + t;
        if (n < N_NODES) {
            int h = histS[0][t] + histS[1][t] + histS[2][t] + histS[3][t];
            deg[n] = h;
            float d = rsqrtf((float)h + 1.0f);
            dis[n] = d;
            float2 xa = *(const float2*)&x[n * IN_DIM + 0];
            float2 xb = *(const float2*)&x[n * IN_DIM + 2];
            float2 xc = *(const float2*)&x[n * IN_DIM + 4];
            uint4 u;
            u.x = pack2(xa.x * d, xa.y * d);
            u.y = pack2(xb.x * d, xb.y * d);
            u.z = pack2(xc.x * d, xc.y * d);
            u.w = 0;
            xpad[n] = u;
        }
    }
}

// --- aggW: fused per-bin pipeline ------------------------------------------
__global__ __launch_bounds__(1024) void aggW(const unsigned* __restrict__ rec,
                                             const int* __restrict__ cnt,
                                             const int* __restrict__ deg,
                                             const float* __restrict__ dis,
                                             const uint4* __restrict__ xpad,
                                             const float* __restrict__ W1,
                                             const float* __restrict__ b1,
                                             float* __restrict__ vsum) {
    __shared__ unsigned srcL[CAP];          // 16 KB sorted src ids
    __shared__ float wlS[4][BIN_NODES];     // 4 KB wsum sub-accumulators
    __shared__ int degL[BIN_NODES];
    __shared__ int startS[BIN_NODES];
    __shared__ int cur[BIN_NODES];
    __shared__ int sc[BIN_NODES];
    __shared__ float sAll[BIN_NODES][8];    // s6 sums + d + cw
    __shared__ float w1s[IN_DIM * HID];     // [k][c]
    __shared__ float b1s[HID];
    __shared__ float vpart[HID];
    int t = threadIdx.x, g = t >> 8;
    int bin = blockIdx.x;

    if (t < 4 * BIN_NODES) ((float*)wlS)[t] = 0.f;
    if (t < IN_DIM * HID) w1s[t] = W1[t];
    if (t >= 1024 - HID) { int c = t - (1024 - HID); b1s[c] = b1[c]; vpart[c] = 0.f; }
    __syncthreads();

    // phase A: local wsum from src-chain
    {
        int beg = SOFF + bin * CAP, end = beg + cnt[NBIN + bin];
        for (int j = beg + t; j < end; j += 1024) {
            unsigned r = rec[j];
            atomicAdd(&wlS[g][r >> 17], dis[r & 131071u]);
        }
    }
    __syncthreads();

    // phase B: deg -> scan -> offsets; d, cw
    if (t < BIN_NODES) {
        int n = (bin << BIN_SHIFT) + t;
        int h = (n < N_NODES) ? deg[n] : 0;
        degL[t] = h;
        sc[t] = h;
        float d = (n < N_NODES) ? rsqrtf((float)h + 1.0f) : 0.f;
        float wloc = wlS[0][t] + wlS[1][t] + wlS[2][t] + wlS[3][t];
        sAll[t][6] = d;
        sAll[t][7] = (n < N_NODES) ? d * (wloc + d) : 0.f;
    }
    __syncthreads();
    for (int off = 1; off < BIN_NODES; off <<= 1) {
        int add = 0;
        if (t < BIN_NODES && t >= off) add = sc[t - off];
        __syncthreads();
        if (t < BIN_NODES) sc[t] += add;
        __syncthreads();
    }
    if (t < BIN_NODES) {
        int st = sc[t] - degL[t];
        startS[t] = st;
        cur[t] = st;
    }
    __syncthreads();

    // phase C: counting-sort scatter (dst-chain)
    {
        int beg = bin * CAP, end = beg + cnt[bin];
        for (int j = beg + t; j < end; j += 1024) {
            unsigned r = rec[j];
            int pos = atomicAdd(&cur[r >> 17], 1);
            if (pos < CAP) srcL[pos] = r & 131071u;
        }
    }
    __syncthreads();

    // phase D: 4 threads/node register accumulation
    {
        int node = t >> 2, sub = t & 3;
        int st = startS[node], cn = degL[node];
        int lim = min(st + cn, CAP);
        float s0 = 0.f, s1 = 0.f, s2 = 0.f, s3 = 0.f, s4 = 0.f, s5 = 0.f;
        for (int k = st + sub; k < lim; k += 4) {
            uint4 px = xpad[srcL[k]];
            s0 += lo16(px.x); s1 += hi16(px.x);
            s2 += lo16(px.y); s3 += hi16(px.y);
            s4 += lo16(px.z); s5 += hi16(px.z);
        }
        s0 += __shfl_xor(s0, 1, 64); s0 += __shfl_xor(s0, 2, 64);
        s1 += __shfl_xor(s1, 1, 64); s1 += __shfl_xor(s1, 2, 64);
        s2 += __shfl_xor(s2, 1, 64); s2 += __shfl_xor(s2, 2, 64);
        s3 += __shfl_xor(s3, 1, 64); s3 += __shfl_xor(s3, 2, 64);
        s4 += __shfl_xor(s4, 1, 64); s4 += __shfl_xor(s4, 2, 64);
        s5 += __shfl_xor(s5, 1, 64); s5 += __shfl_xor(s5, 2, 64);
        if (sub == 0) {
            int n = (bin << BIN_SHIFT) + node;
            if (n < N_NODES) {                  // self term
                uint4 px = xpad[n];
                s0 += lo16(px.x); s1 += hi16(px.x);
                s2 += lo16(px.y); s3 += hi16(px.y);
                s4 += lo16(px.z); s5 += hi16(px.z);
            }
            sAll[node][0] = s0; sAll[node][1] = s1; sAll[node][2] = s2;
            sAll[node][3] = s3; sAll[node][4] = s4; sAll[node][5] = s5;
        }
    }
    __syncthreads();

    // phase E: 16 groups x 64 lanes; lane = channel, sAll broadcast reads
    {
        int c = t & 63, grp = t >> 6;
        float v = 0.f;
#pragma unroll
        for (int i = 0; i < 16; ++i) {
            int node = grp * 16 + i;
            float d = sAll[node][6], cw = sAll[node][7];
            float a = sAll[node][0] * w1s[0 * HID + c]
                    + sAll[node][1] * w1s[1 * HID + c]
                    + sAll[node][2] * w1s[2 * HID + c]
                    + sAll[node][3] * w1s[3 * HID + c]
                    + sAll[node][4] * w1s[4 * HID + c]
                    + sAll[node][5] * w1s[5 * HID + c];
            v += cw * fmaxf(d * a + b1s[c], 0.f);
        }
        atomicAdd(&vpart[c], v);
    }
    __syncthreads();
    if (t < HID) atomicAdd(&vsum[t], vpart[t]);
}

// --- final: g = b2 + (vsum/N) @ W2 ; out = sigmoid(g @ Wfc + bfc) ----------
__global__ void finalK(const float* __restrict__ vsum, const float* __restrict__ W2,
                       const float* __restrict__ b2, const float* __restrict__ Wfc,
                       const float* __restrict__ bfc, float* __restrict__ out) {
    __shared__ float vL[HID];
    int t = threadIdx.x;
    vL[t] = vsum[t] * (1.0f / N_NODES);
    __syncthreads();
    float g = b2[t];
    for (int k = 0; k < HID; ++k) g += vL[k] * W2[k * HID + t];
    float z = g * Wfc[t];
    for (int off = 32; off > 0; off >>= 1) z += __shfl_down(z, off, 64);
    if (t == 0) out[0] = 1.0f / (1.0f + expf(-(z + bfc[0])));
}

extern "C" void kernel_launch(void* const* d_in, const int* in_sizes, int n_in,
                              void* d_out, int out_size, void* d_ws, size_t ws_size,
                              hipStream_t stream) {
    const float* x   = (const float*)d_in[0];
    const int*   ei  = (const int*)d_in[1];   // (2, E) row-major int32
    const float* W1  = (const float*)d_in[2];
    const float* b1  = (const float*)d_in[3];
    const float* W2  = (const float*)d_in[4];
    const float* b2  = (const float*)d_in[5];
    const float* Wfc = (const float*)d_in[6];
    const float* bfc = (const float*)d_in[7];
    const int* src = ei;
    const int* dst = ei + N_EDGES;

    char* ws = (char*)d_ws;
    size_t off = 0;
    auto alloc = (+[](char* base, size_t* o, size_t bytes) {
        char* p = base + *o;
        *o += (bytes + 255) & ~(size_t)255;
        return p;
    });
    int*      cnt  = (int*)     alloc(ws, &off, (size_t)2 * NBIN * 4);   // 3128 B -> 3328
    float*    vsum = (float*)   alloc(ws, &off, 64 * 4);                 // adjacent to cnt
    uint4*    xpad = (uint4*)   alloc(ws, &off, (size_t)N_NODES * 16);
    float*    dis  = (float*)   alloc(ws, &off, (size_t)N_NODES * 4);
    int*      deg  = (int*)     alloc(ws, &off, (size_t)N_NODES * 4);
    unsigned* rec  = (unsigned*)alloc(ws, &off, (size_t)2 * SOFF * 4);   // 12.8 MB

    // one memset covers cnt (padded) + vsum
    hipMemsetAsync(cnt, 0, ((size_t)2 * NBIN * 4 + 255 & ~(size_t)255) + 64 * 4, stream);

    binFill<<<A_BLOCKS, 1024, 0, stream>>>(src, dst, cnt, rec);
    disXH<<<NBIN, 1024, 0, stream>>>(rec, cnt, x, deg, dis, xpad);
    aggW<<<NBIN, 1024, 0, stream>>>(rec, cnt, deg, dis, xpad, W1, b1, vsum);
    finalK<<<1, 64, 0, stream>>>(vsum, W2, b2, Wfc, bfc, (float*)d_out);
}